// Round 1
// baseline (1124.298 us; speedup 1.0000x reference)
//
#include <hip/hip_runtime.h>

typedef __bf16 bf16;
typedef __bf16 bf16x8 __attribute__((ext_vector_type(8)));
typedef __bf16 bf16x4 __attribute__((ext_vector_type(4)));
typedef float  f32x4  __attribute__((ext_vector_type(4)));

#define N_TOK 8192
#define IN_F  4096
#define OUT_F 4096
#define STEP  0.0078125f

// ---------------------------------------------------------------------------
// Kernel 1: w[o][i] = bf16( (sum_k w_twos[o][i][k] * base[k]) * STEP )
// One thread per (o,i): 32B contiguous read per lane (2x float4), bf16 write.
// HBM-bound: 512 MiB in + 32 MiB out.
// ---------------------------------------------------------------------------
__global__ void __launch_bounds__(256) reconstruct_w(
    const float* __restrict__ wt, const float* __restrict__ base,
    bf16* __restrict__ w) {
  long idx = (long)blockIdx.x * 256 + threadIdx.x;
  const float4* p = (const float4*)wt + idx * 2;
  float4 lo = p[0];
  float4 hi = p[1];
  // base is uniform -> scalar loads
  float s = lo.x * base[0] + lo.y * base[1] + lo.z * base[2] + lo.w * base[3]
          + hi.x * base[4] + hi.y * base[5] + hi.z * base[6] + hi.w * base[7];
  w[idx] = (bf16)(s * STEP);
}

// ---------------------------------------------------------------------------
// Kernel 2: x fp32 -> bf16 (4 elements/thread, float4 in, 8B out)
// ---------------------------------------------------------------------------
__global__ void __launch_bounds__(256) cvt_x(
    const float* __restrict__ x, bf16* __restrict__ xb) {
  long idx = (long)blockIdx.x * 256 + threadIdx.x;
  float4 v = ((const float4*)x)[idx];
  bf16x4 o = { (bf16)v.x, (bf16)v.y, (bf16)v.z, (bf16)v.w };
  *(bf16x4*)(xb + idx * 4) = o;
}

// ---------------------------------------------------------------------------
// Kernel 3: C[m][n] = sum_k A[m][k]*B[n][k] + bias[n]   (A: MxK, B: NxK bf16)
// m97-ladder structure: 128x128 block tile, BK=32, 256 threads = 4 waves in
// 2x2, each wave does a 64x64 tile as 4x4 mfma_f32_16x16x32_bf16.
// Staging via global_load_lds width=16; LDS layout is unpadded row-major
// (required: lds dest is wave-uniform base + lane*16).
// ---------------------------------------------------------------------------
__device__ __forceinline__ void async16(const bf16* g, bf16* l) {
  __builtin_amdgcn_global_load_lds(
      (__attribute__((address_space(1))) void*)(bf16*)g,
      (__attribute__((address_space(3))) void*)l,
      16, 0, 0);
}

__global__ void __launch_bounds__(256) gemm_bt(
    const bf16* __restrict__ A, const bf16* __restrict__ B,
    const float* __restrict__ bias, float* __restrict__ C) {
  __shared__ bf16 sA[128 * 32];  // 8 KiB, row-major, row stride 32
  __shared__ bf16 sB[128 * 32];  // 8 KiB

  const int tid  = threadIdx.x;
  const int lane = tid & 63;
  const int wave = tid >> 6;
  const int m0 = (wave >> 1) * 64;   // wave tile origin inside block tile
  const int n0 = (wave & 1) * 64;
  const int lrow = lane & 15;        // A/B operand: row (m or n) = lane&15
  const int lk   = (lane >> 4) * 8;  // k offset = quad*8

  const long rowBaseA = (long)blockIdx.y * 128;  // token rows
  const long rowBaseB = (long)blockIdx.x * 128;  // output features

  // staging chunks: tile = 512 x 16B chunks; thread t does chunks t, t+256.
  // chunk c -> LDS bytes [c*16, c*16+16) -> row c>>2, elem offset (c&3)*8.
  const int c0 = tid, c1 = tid + 256;
  const int ar0 = c0 >> 2, ao0 = (c0 & 3) * 8;
  const int ar1 = c1 >> 2, ao1 = (c1 & 3) * 8;

  const bf16* Abase = A + rowBaseA * IN_F;
  const bf16* Bbase = B + rowBaseB * IN_F;

  f32x4 acc[4][4] = {};

  for (int kt = 0; kt < IN_F; kt += 32) {
    async16(Abase + (long)ar0 * IN_F + kt + ao0, &sA[c0 * 8]);
    async16(Abase + (long)ar1 * IN_F + kt + ao1, &sA[c1 * 8]);
    async16(Bbase + (long)ar0 * IN_F + kt + ao0, &sB[c0 * 8]);
    async16(Bbase + (long)ar1 * IN_F + kt + ao1, &sB[c1 * 8]);
    __syncthreads();  // compiler emits vmcnt(0) drain before s_barrier

    bf16x8 af[4], bfr[4];
#pragma unroll
    for (int t = 0; t < 4; ++t)
      af[t] = *(const bf16x8*)&sA[(m0 + t * 16 + lrow) * 32 + lk];
#pragma unroll
    for (int t = 0; t < 4; ++t)
      bfr[t] = *(const bf16x8*)&sB[(n0 + t * 16 + lrow) * 32 + lk];

#pragma unroll
    for (int i = 0; i < 4; ++i)
#pragma unroll
      for (int j = 0; j < 4; ++j)
        acc[i][j] = __builtin_amdgcn_mfma_f32_16x16x32_bf16(
            af[i], bfr[j], acc[i][j], 0, 0, 0);

    __syncthreads();
  }

  // Epilogue: C/D layout col = lane&15, row = (lane>>4)*4 + reg.
#pragma unroll
  for (int j = 0; j < 4; ++j) {
    const long gn = rowBaseB + n0 + j * 16 + (lane & 15);
    const float bj = bias[gn];
#pragma unroll
    for (int i = 0; i < 4; ++i) {
      const long gm = rowBaseA + m0 + i * 16 + (lane >> 4) * 4;
#pragma unroll
      for (int r = 0; r < 4; ++r) {
        C[(gm + r) * OUT_F + gn] = acc[i][j][r] + bj;
      }
    }
  }
}

// ---------------------------------------------------------------------------
extern "C" void kernel_launch(void* const* d_in, const int* in_sizes, int n_in,
                              void* d_out, int out_size, void* d_ws, size_t ws_size,
                              hipStream_t stream) {
  const float* x      = (const float*)d_in[0];  // [8192, 4096]
  const float* w_twos = (const float*)d_in[1];  // [4096, 4096, 8]
  const float* b      = (const float*)d_in[2];  // [4096]
  const float* base   = (const float*)d_in[3];  // [8]
  float* out = (float*)d_out;                   // [8192, 4096]

  bf16* wbf = (bf16*)d_ws;                         // 4096*4096 bf16 = 32 MiB
  bf16* xbf = wbf + (size_t)OUT_F * IN_F;          // 8192*4096 bf16 = 64 MiB

  reconstruct_w<<<(OUT_F * IN_F) / 256, 256, 0, stream>>>(w_twos, base, wbf);
  cvt_x<<<(N_TOK * IN_F) / (256 * 4), 256, 0, stream>>>(x, xbf);

  dim3 grid(OUT_F / 128, N_TOK / 128);  // 32 x 64 = 2048 blocks
  gemm_bt<<<grid, dim3(256), 0, stream>>>(xbf, wbf, b, out);
}